// Round 5
// baseline (784.238 us; speedup 1.0000x reference)
//
#include <hip/hip_runtime.h>
#include <math.h>

namespace {
constexpr int kBL = 16 * 2048;
constexpr int kH = 256;
constexpr int kNOut = 12;
constexpr int kRows = 64;        // rows per block
constexpr int kThreads = 1024;   // 16 waves; wave wv owns gate-cols wv*16..+15 (x3 gates)
constexpr int kS = 264;          // LDS row stride in shorts
constexpr int kWhh = 3 * kH * kH;
}

using short8 = __attribute__((ext_vector_type(8))) short;
using f32x4 = __attribute__((ext_vector_type(4))) float;

__device__ inline void bsplit(float v, short& h, short& l) {
  unsigned u = __float_as_uint(v);
  unsigned rh = u + 0x7FFFu + ((u >> 16) & 1u);   // RNE to bf16
  h = (short)(rh >> 16);
  float hf = __uint_as_float(rh & 0xFFFF0000u);
  float r = v - hf;                                // exact residual
  unsigned u2 = __float_as_uint(r);
  unsigned rl = u2 + 0x7FFFu + ((u2 >> 16) & 1u);
  l = (short)(rl >> 16);
}

// split w_hh [768][256] fp32 -> bf16 hi/lo planes in d_ws
__global__ void split_whh_kernel(const float* __restrict__ w,
                                 short* __restrict__ hi, short* __restrict__ lo) {
  const int i = (blockIdx.x * 256 + threadIdx.x) * 4;
  const float4 v = *reinterpret_cast<const float4*>(w + i);
  short4 h4, l4;
  bsplit(v.x, h4.x, l4.x);
  bsplit(v.y, h4.y, l4.y);
  bsplit(v.z, h4.z, l4.z);
  bsplit(v.w, h4.w, l4.w);
  *reinterpret_cast<short4*>(hi + i) = h4;
  *reinterpret_cast<short4*>(lo + i) = l4;
}

#define MFMA(A, B, C) __builtin_amdgcn_mfma_f32_16x16x32_bf16((A), (B), (C), 0, 0, 0)

__global__ __launch_bounds__(kThreads, 4)
void rbq_mfma4_kernel(const float* __restrict__ emb,    // [BL][256]
                      const float* __restrict__ w_ih,   // [768]
                      const float* __restrict__ b_ih,   // [768]
                      const float* __restrict__ b_hh,   // [768]
                      const float* __restrict__ w_out,  // [256]
                      const float* __restrict__ b_out,  // [1]
                      const short* __restrict__ Bh,     // [768][256] bf16 hi
                      const short* __restrict__ Bl,     // [768][256] bf16 lo
                      float* __restrict__ out) {        // [2][BL][12]
  // Double-buffered A: MFMA(step) reads buf p while gates(step) write buf p^1.
  // -> exactly ONE __syncthreads per step.
  __shared__ short Ah[2][kRows][kS];
  __shared__ short Al[2][kRows][kS];
  __shared__ float osc[kRows][16];   // per-wave o partials

  const int tid = threadIdx.x;
  const int lane = tid & 63;
  const int wv = __builtin_amdgcn_readfirstlane(tid >> 6);  // 0..15
  const int grp = lane >> 4;
  const int c16 = lane & 15;
  const int row0 = blockIdx.x * kRows;
  const int j = wv * 16 + c16;      // this lane's H column

  // per-lane gate constants (identical numerics to round 4)
  const float wihr = w_ih[j], wihz = w_ih[kH + j], wihn = w_ih[2 * kH + j];
  const float bihr = b_ih[j], bihz = b_ih[kH + j], bihn = b_ih[2 * kH + j];
  const float bhhr = b_hh[j], bhhz = b_hh[kH + j], bhhn = b_hh[2 * kH + j];
  const float wo = w_out[j];
  const float bo = b_out[0];
  const size_t q_off = (size_t)kBL * kNOut;

  // init: h0 = 0 -> h_in = e; exact h_in in regs, split copy in LDS buf 0
  float h_reg[4][4];
#pragma unroll
  for (int m = 0; m < 4; ++m)
#pragma unroll
    for (int r = 0; r < 4; ++r) {
      const int rl = m * 16 + grp * 4 + r;
      const float e = emb[(size_t)(row0 + rl) * kH + j];
      h_reg[m][r] = e;
      short hh, hl;
      bsplit(e, hh, hl);
      Ah[0][rl][j] = hh;
      Al[0][rl][j] = hl;
    }
  float xqr = 0.0f;                  // q feedback for row == lane
  __syncthreads();

  int p = 0;
  for (int step = 0; step < kNOut; ++step) {
    // ---- MFMA phase: gh for this wave's 16 cols x 3 gates, all 64 rows ----
    f32x4 acc[4][3];
#pragma unroll
    for (int m = 0; m < 4; ++m) {
      acc[m][0] = f32x4{bhhr, bhhr, bhhr, bhhr};
      acc[m][1] = f32x4{bhhz, bhhz, bhhz, bhhz};
      acc[m][2] = f32x4{bhhn, bhhn, bhhn, bhhn};
    }

    __builtin_amdgcn_s_setprio(1);
#pragma unroll 1
    for (int kc = 0; kc < 8; ++kc) {
      const int ko = kc * 32 + grp * 8;
      short8 bh[3], bl[3];
#pragma unroll
      for (int g = 0; g < 3; ++g) {
        const size_t base = (size_t)(g * kH + j) * kH + ko;
        bh[g] = *reinterpret_cast<const short8*>(Bh + base);
        bl[g] = *reinterpret_cast<const short8*>(Bl + base);
      }
#pragma unroll
      for (int m = 0; m < 4; ++m) {
        const short8 ah = *reinterpret_cast<const short8*>(&Ah[p][m * 16 + c16][ko]);
        const short8 al = *reinterpret_cast<const short8*>(&Al[p][m * 16 + c16][ko]);
        // per-acc pass order identical to rounds 2/4: ah*bh, al*bh, ah*bl
#pragma unroll
        for (int g = 0; g < 3; ++g) acc[m][g] = MFMA(ah, bh[g], acc[m][g]);
#pragma unroll
        for (int g = 0; g < 3; ++g) acc[m][g] = MFMA(al, bh[g], acc[m][g]);
#pragma unroll
        for (int g = 0; g < 3; ++g) acc[m][g] = MFMA(ah, bl[g], acc[m][g]);
      }
    }
    __builtin_amdgcn_s_setprio(0);

    // ---- gate phase: lane owns rows m*16+grp*4+r at col j; writes A buf p^1 ----
    float opart[4][4];
#pragma unroll
    for (int m = 0; m < 4; ++m) {
#pragma unroll
      for (int r = 0; r < 4; ++r) {
        const int rl = m * 16 + grp * 4 + r;
        const float x = __shfl(xqr, rl);              // q(step-1) for row rl
        const float ghr = acc[m][0][r];
        const float ghz = acc[m][1][r];
        const float ghn = acc[m][2][r];
        const float gr = fmaf(x, wihr, bihr) + ghr;   // round-4 exact expr
        const float gz = fmaf(x, wihz, bihz) + ghz;
        const float gni = fmaf(x, wihn, bihn);
        const float rg = 1.0f / (1.0f + __expf(-gr));
        const float zg = 1.0f / (1.0f + __expf(-gz));
        const float ta = gni + rg * ghn;
        const float at = fabsf(ta);
        const float et = __expf(-2.0f * at);
        const float th = copysignf((1.0f - et) / (1.0f + et), ta);
        const float hn = fmaf(zg, h_reg[m][r] - th, th);   // (1-z)*n + z*h_in
        opart[m][r] = hn * wo;
        const float hnext = hn + emb[(size_t)(row0 + rl) * kH + j];
        h_reg[m][r] = hnext;
        short hh, hl;
        bsplit(hnext, hh, hl);
        Ah[p ^ 1][rl][j] = hh;
        Al[p ^ 1][rl][j] = hl;
      }
    }

    // exact-fp32 o: butterfly over the 16 cols of this wave (same order as r4)
#pragma unroll
    for (int m = 0; m < 4; ++m)
#pragma unroll
      for (int r = 0; r < 4; ++r) {
#pragma unroll
        for (int mask = 1; mask < 16; mask <<= 1)
          opart[m][r] += __shfl_xor(opart[m][r], mask, 16);
      }
    if (c16 == 0) {
#pragma unroll
      for (int m = 0; m < 4; ++m)
#pragma unroll
        for (int r = 0; r < 4; ++r)
          osc[m * 16 + grp * 4 + r][wv] = opart[m][r];
    }
    __syncthreads();   // A(p^1) complete + osc ready (the ONLY barrier)

    // ---- per-wave finalize for row == lane: o, q, feedback register ----
    {
      const float4 o0 = *reinterpret_cast<const float4*>(&osc[lane][0]);
      const float4 o1 = *reinterpret_cast<const float4*>(&osc[lane][4]);
      const float4 o2 = *reinterpret_cast<const float4*>(&osc[lane][8]);
      const float4 o3 = *reinterpret_cast<const float4*>(&osc[lane][12]);
      float s = bo;                                   // same order as r4: bo first,
      s += o0.x; s += o0.y; s += o0.z; s += o0.w;     // then waves 0..15 ascending
      s += o1.x; s += o1.y; s += o1.z; s += o1.w;
      s += o2.x; s += o2.y; s += o2.z; s += o2.w;
      s += o3.x; s += o3.y; s += o3.z; s += o3.w;
      const float q = s > 0.0f ? 1.0f : -1.0f;
      xqr = q;
      if (wv == 0) {
        const size_t gr = (size_t)(row0 + lane);
        out[gr * kNOut + step] = s;
        out[q_off + gr * kNOut + step] = q;
      }
    }
    p ^= 1;
  }
}

extern "C" void kernel_launch(void* const* d_in, const int* in_sizes, int n_in,
                              void* d_out, int out_size, void* d_ws, size_t ws_size,
                              hipStream_t stream) {
  (void)in_sizes; (void)n_in; (void)out_size; (void)ws_size;
  const float* emb = (const float*)d_in[0];
  const float* w_ih = (const float*)d_in[1];
  const float* w_hh = (const float*)d_in[2];
  const float* b_ih = (const float*)d_in[3];
  const float* b_hh = (const float*)d_in[4];
  const float* w_out = (const float*)d_in[5];
  const float* b_out = (const float*)d_in[6];

  short* Bh = (short*)d_ws;                  // [768][256] bf16 hi
  short* Bl = Bh + kWhh;                     // [768][256] bf16 lo (768 KiB total)

  split_whh_kernel<<<kWhh / (256 * 4), 256, 0, stream>>>(w_hh, Bh, Bl);
  rbq_mfma4_kernel<<<kBL / kRows, kThreads, 0, stream>>>(
      emb, w_ih, b_ih, b_hh, w_out, b_out, Bh, Bl, (float*)d_out);
}